// Round 11
// baseline (373.694 us; speedup 1.0000x reference)
//
#include <hip/hip_runtime.h>
#include <math.h>

#define NN 100000
#define DD 128
#define NB 391          // row buckets of 256 rows: (100000+255)>>8
#define RP_PAD 100004   // row_ptr elems, padded for 16B alignment

typedef short bf16x8 __attribute__((ext_vector_type(8)));
typedef float f32x4  __attribute__((ext_vector_type(4)));
typedef unsigned uint4v __attribute__((ext_vector_type(4)));

__device__ __forceinline__ unsigned f2bf_rne(float f) {
    unsigned u = __float_as_uint(f);
    return (u + 0x7FFFu + ((u >> 16) & 1u)) >> 16;
}
__device__ __forceinline__ unsigned packbf(float a, float b) {
    return f2bf_rne(a) | (f2bf_rne(b) << 16);
}
__device__ __forceinline__ float bf_lo(unsigned u) { return __uint_as_float(u << 16); }
__device__ __forceinline__ float bf_hi(unsigned u) { return __uint_as_float(u & 0xFFFF0000u); }

// non-temporal 8B edge load — CSR-build use only (single-pass streams).
// NOT used in spmm gathers (round-1: NT there = +36MB fetch, -10% BW).
__device__ __forceinline__ int2 ldnt_edge(const int2* p) {
    long long v = __builtin_nontemporal_load((const long long*)p);
    int2 r;
    r.x = (int)(v & 0xffffffffll);
    r.y = (int)(((unsigned long long)v) >> 32);
    return r;
}

// ---------------------------------------------------------------------------
// Launch 2 (merged): bucketed scatter + ALL converts (round-10 form).
// Bucketing ESSENTIAL (rounds 4/7: random global RMWs are line-churn bound
// — keep them in LDS). 8192-edge chunks x 1024 thr (rounds 5/6), edges
// register-cached (round 8). Converts backfill CUs during scatter.
// ---------------------------------------------------------------------------
__global__ __launch_bounds__(1024) void scatter_convert(
    const int* __restrict__ row, const int* __restrict__ col,
    const float* __restrict__ vals, int* __restrict__ bcnt,
    int2* __restrict__ ep_raw, int E, int CAP, int cb,
    const float* __restrict__ vecs, unsigned short* __restrict__ vecs_bf,
    const float* __restrict__ W0, const float* __restrict__ W1,
    const float* __restrict__ W2, unsigned short* __restrict__ Wt, int n8)
{
    const int b = blockIdx.x;
    const int t = threadIdx.x;

    if (b >= cb) {
        const int b2 = b - cb;
        if (b2 < 6) {
            const int m = b2 >> 1;
            const float* W = (m == 0) ? W0 : ((m == 1) ? W1 : W2);
            unsigned short* dst = Wt + m * DD * DD;
            int idx = (b2 & 1) * 1024 + t;     // 0..2047
            int n = idx >> 4;
            int kc = (idx & 15) * 8;
            unsigned r[4];
            #pragma unroll
            for (int j = 0; j < 4; j++) {
                float a = W[(kc + 2 * j) * DD + n];
                float c = W[(kc + 2 * j + 1) * DD + n];
                r[j] = packbf(a, c);
            }
            *(uint4*)(dst + n * DD + kc) = make_uint4(r[0], r[1], r[2], r[3]);
        } else {
            int i = (b2 - 6) * 1024 + t;
            if (i >= n8) return;
            f32x4 a = __builtin_nontemporal_load((const f32x4*)vecs + (size_t)i * 2);
            f32x4 c = __builtin_nontemporal_load((const f32x4*)vecs + (size_t)i * 2 + 1);
            uint4v o;
            o.x = packbf(a.x, a.y); o.y = packbf(a.z, a.w);
            o.z = packbf(c.x, c.y); o.w = packbf(c.z, c.w);
            ((uint4v*)vecs_bf)[i] = o;
        }
        return;
    }

    __shared__ int cnt[NB];
    __shared__ int base[NB];
    if (t < NB) cnt[t] = 0;
    __syncthreads();
    const int eb = b * 8192;
    const int ee = min(eb + 8192, E);

    int   rr[8];
    int   cc[8];
    float vv[8];
    #pragma unroll
    for (int i = 0; i < 8; i++) {
        int j = eb + t + i * 1024;
        rr[i] = -1;
        if (j < ee) {
            rr[i] = row[j];
            cc[i] = __builtin_nontemporal_load(col + j);
            vv[i] = __builtin_nontemporal_load(vals + j);
            atomicAdd(&cnt[rr[i] >> 8], 1);
        }
    }
    __syncthreads();
    if (t < NB) {
        int c = cnt[t];
        base[t] = c ? (t * CAP + atomicAdd(&bcnt[t], c)) : 0;
        cnt[t] = 0;
    }
    __syncthreads();
    #pragma unroll
    for (int i = 0; i < 8; i++) {
        int r = rr[i];
        if (r >= 0) {
            int bk = r >> 8;
            int off = atomicAdd(&cnt[bk], 1);
            unsigned meta = (unsigned)cc[i] | ((unsigned)(r & 255) << 17);
            ep_raw[base[bk] + off] = make_int2((int)meta, __float_as_int(vv[i]));
        }
    }
}

// ---------------------------------------------------------------------------
// Launch 3: CSR compaction (round-10 form, 1024-thr blocks). Per-bucket
// LDS hist over the L2-hot span (round-7: global row hist = line churn).
// ---------------------------------------------------------------------------
__global__ __launch_bounds__(1024) void csr_compact(
    const int* __restrict__ bcnt, const int2* __restrict__ ep_raw,
    int* __restrict__ row_ptr, int2* __restrict__ ep,
    int CAP, int N, int E)
{
    __shared__ int red[1024];
    __shared__ int rcnt[256];
    __shared__ int rcur[256];
    __shared__ int wsum[4];
    const int b = blockIdx.x;
    const int t = threadIdx.x;

    int part = 0;
    for (int j = t; j < b; j += 1024) part += bcnt[j];
    red[t] = part;
    __syncthreads();
    #pragma unroll
    for (int off = 512; off > 0; off >>= 1) {
        if (t < off) red[t] += red[t + off];
        __syncthreads();
    }
    const int dst = red[0];
    const int cnt = bcnt[b];
    const int src = b * CAP;

    if (t < 256) rcnt[t] = 0;
    __syncthreads();
    for (int j = t; j < cnt; j += 1024)
        atomicAdd(&rcnt[(unsigned)ep_raw[src + j].x >> 17], 1);
    __syncthreads();

    int v = 0, inc = 0;
    const int lane = t & 63;
    if (t < 256) {
        v = rcnt[t];
        inc = v;
        #pragma unroll
        for (int off = 1; off < 64; off <<= 1) {
            int u = __shfl_up(inc, off, 64);
            if (lane >= off) inc += u;
        }
        if (lane == 63) wsum[t >> 6] = inc;
    }
    __syncthreads();
    if (t < 256) {
        int woff = 0;
        for (int i = 0; i < (t >> 6); i++) woff += wsum[i];
        int excl = woff + inc - v;
        int grow = b * 256 + t;
        if (grow < N) row_ptr[grow] = dst + excl;
        rcur[t] = excl;
    }
    __syncthreads();

    for (int j = t; j < cnt; j += 1024) {
        int2 rec = ldnt_edge(ep_raw + src + j);
        unsigned meta = (unsigned)rec.x;
        int rlo = meta >> 17;
        int c = (int)(meta & 0x1FFFFu);
        int p = atomicAdd(&rcur[rlo], 1);
        ep[dst + p] = make_int2(c, rec.y);
    }
    if (b == 0 && t == 0) row_ptr[N] = E;
}

// ---------------------------------------------------------------------------
// Row-gather (spmm core, frozen since round 2): one CSR row per 16-lane
// group, 16B/lane, fp32 accumulate. CACHED loads (round-1 NT regression).
// FETCH 183MB == private-L2 compulsory floor; 3.4 TB/s == random-granule
// fabric rate. Round-9: NEVER barrier-chain this with MFMA in one block.
// ---------------------------------------------------------------------------
__device__ __forceinline__ void accum8(float* acc, uint4 u, float v) {
    acc[0] += v * bf_lo(u.x); acc[1] += v * bf_hi(u.x);
    acc[2] += v * bf_lo(u.y); acc[3] += v * bf_hi(u.y);
    acc[4] += v * bf_lo(u.z); acc[5] += v * bf_hi(u.z);
    acc[6] += v * bf_lo(u.w); acc[7] += v * bf_hi(u.w);
}

__device__ __forceinline__ uint4 row_gather(
    const uint4* __restrict__ x, const int2* __restrict__ ep,
    int s, int e, int lane)
{
    float acc[8] = {0.f, 0.f, 0.f, 0.f, 0.f, 0.f, 0.f, 0.f};
    int k = s;
    for (; k + 8 <= e; k += 8) {
        int2 E0 = ep[k + 0], E1 = ep[k + 1], E2 = ep[k + 2], E3 = ep[k + 3];
        int2 E4 = ep[k + 4], E5 = ep[k + 5], E6 = ep[k + 6], E7 = ep[k + 7];
        uint4 X0 = x[(size_t)E0.x * 16 + lane];
        uint4 X1 = x[(size_t)E1.x * 16 + lane];
        uint4 X2 = x[(size_t)E2.x * 16 + lane];
        uint4 X3 = x[(size_t)E3.x * 16 + lane];
        uint4 X4 = x[(size_t)E4.x * 16 + lane];
        uint4 X5 = x[(size_t)E5.x * 16 + lane];
        uint4 X6 = x[(size_t)E6.x * 16 + lane];
        uint4 X7 = x[(size_t)E7.x * 16 + lane];
        accum8(acc, X0, __int_as_float(E0.y));
        accum8(acc, X1, __int_as_float(E1.y));
        accum8(acc, X2, __int_as_float(E2.y));
        accum8(acc, X3, __int_as_float(E3.y));
        accum8(acc, X4, __int_as_float(E4.y));
        accum8(acc, X5, __int_as_float(E5.y));
        accum8(acc, X6, __int_as_float(E6.y));
        accum8(acc, X7, __int_as_float(E7.y));
    }
    for (; k + 4 <= e; k += 4) {
        int2 E0 = ep[k + 0], E1 = ep[k + 1], E2 = ep[k + 2], E3 = ep[k + 3];
        uint4 X0 = x[(size_t)E0.x * 16 + lane];
        uint4 X1 = x[(size_t)E1.x * 16 + lane];
        uint4 X2 = x[(size_t)E2.x * 16 + lane];
        uint4 X3 = x[(size_t)E3.x * 16 + lane];
        accum8(acc, X0, __int_as_float(E0.y));
        accum8(acc, X1, __int_as_float(E1.y));
        accum8(acc, X2, __int_as_float(E2.y));
        accum8(acc, X3, __int_as_float(E3.y));
    }
    for (; k < e; k++) {
        int2 E0 = ep[k];
        uint4 X0 = x[(size_t)E0.x * 16 + lane];
        accum8(acc, X0, __int_as_float(E0.y));
    }
    uint4 o;
    o.x = packbf(acc[0], acc[1]); o.y = packbf(acc[2], acc[3]);
    o.z = packbf(acc[4], acc[5]); o.w = packbf(acc[6], acc[7]);
    return o;
}

// ---------------------------------------------------------------------------
// One dense order: stage W^T (32KB LDS), A-frags from global (nt), MFMA,
// per-row batchnorm via C-layout + shfl_xor. Adds its term into facc.
// ---------------------------------------------------------------------------
__device__ __forceinline__ void bn_accum(
    f32x4* acc, const float* __restrict__ bias, const float* __restrict__ off,
    const float* __restrict__ sc, int i, float facc[8][4])
{
    float bc[8], sv[8], ov[8];
    #pragma unroll
    for (int ct = 0; ct < 8; ct++) {
        int c = ct * 16 + i;
        bc[ct] = bias[c]; sv[ct] = sc[c]; ov[ct] = off[c];
    }
    float s[4] = {0.f, 0.f, 0.f, 0.f};
    float qq[4] = {0.f, 0.f, 0.f, 0.f};
    #pragma unroll
    for (int ct = 0; ct < 8; ct++) {
        #pragma unroll
        for (int r = 0; r < 4; r++) {
            float v = fmaxf(acc[ct][r] + bc[ct], 0.f);
            acc[ct][r] = v;
            s[r] += v;
            qq[r] += v * v;
        }
    }
    #pragma unroll
    for (int r = 0; r < 4; r++) {
        #pragma unroll
        for (int m = 1; m <= 8; m <<= 1) {
            s[r]  += __shfl_xor(s[r],  m, 64);
            qq[r] += __shfl_xor(qq[r], m, 64);
        }
    }
    #pragma unroll
    for (int r = 0; r < 4; r++) {
        float mn = s[r] * 0.0078125f;
        float var = qq[r] * 0.0078125f - mn * mn;
        float rs = rsqrtf(var + 1e-9f);
        #pragma unroll
        for (int ct = 0; ct < 8; ct++)
            facc[ct][r] += sv[ct] * (acc[ct][r] - mn) * rs + ov[ct];
    }
}

__device__ __forceinline__ void dense_order(
    const unsigned short* __restrict__ h, const uint4* __restrict__ Wg,
    uint4* Bl, const float* __restrict__ bias,
    const float* __restrict__ off, const float* __restrict__ sc,
    int tid, int i, int q, int arow, float facc[8][4])
{
    #pragma unroll
    for (int j = 0; j < 8; j++) {
        int c  = j * 256 + tid;
        int nn = c & 127;
        int kc = c >> 7;
        Bl[kc * 128 + nn] = Wg[nn * 16 + kc];
    }
    __syncthreads();
    const bf16x8* Bv = (const bf16x8*)Bl;
    const unsigned short* arow_p = h + (size_t)arow * DD + q * 8;
    f32x4 acc[8];
    #pragma unroll
    for (int ct = 0; ct < 8; ct++) acc[ct] = (f32x4){0.f, 0.f, 0.f, 0.f};
    #pragma unroll
    for (int kb = 0; kb < 4; kb++) {
        bf16x8 a = __builtin_nontemporal_load((const bf16x8*)(arow_p + kb * 32));
        const int kc = kb * 4 + q;
        #pragma unroll
        for (int ct = 0; ct < 8; ct++) {
            bf16x8 b = Bv[kc * 128 + ct * 16 + i];
            acc[ct] = __builtin_amdgcn_mfma_f32_16x16x32_bf16(a, b, acc[ct], 0, 0, 0);
        }
    }
    bn_accum(acc, bias, off, sc, i, facc);
}

// ---------------------------------------------------------------------------
// Round-11 co-scheduled dispatches: spmm blocks and dense-order blocks
// INTERLEAVED 4:1 by blockIdx in ONE launch (different blocks — NOT
// round-9's intra-block fusion, which halved gather BW). Dense orders are
// BN-independent; partials accumulate through d_out in fp32 in the same
// order as the monolithic kernel -> bit-identical result.
// ---------------------------------------------------------------------------
__global__ __launch_bounds__(256) void spmm1_dense0(
    const uint4* __restrict__ xv, const int* __restrict__ row_ptr,
    const int2* __restrict__ ep, uint4* __restrict__ hop1,
    const unsigned short* __restrict__ h0,
    const unsigned short* __restrict__ Wt,
    const float* __restrict__ b0, const float* __restrict__ off0,
    const float* __restrict__ sc0, float* __restrict__ out, int N)
{
    __shared__ uint4 Bl[2048];
    const int q5 = blockIdx.x / 5;
    const int r5 = blockIdx.x % 5;
    if (r5 < 4) {
        int t = (q5 * 4 + r5) * 256 + threadIdx.x;
        int g = t >> 4;
        int lane = t & 15;
        if (g >= N) return;
        hop1[(size_t)g * 16 + lane] =
            row_gather(xv, ep, row_ptr[g], row_ptr[g + 1], lane);
        return;
    }
    const int tid = threadIdx.x;
    const int wave = tid >> 6;
    const int lane = tid & 63;
    const int i = lane & 15;
    const int q = lane >> 4;
    const int slab = q5 * 64 + wave * 16;
    int arow = slab + i;
    if (arow >= N) arow = N - 1;
    float facc[8][4];
    #pragma unroll
    for (int ct = 0; ct < 8; ct++)
        #pragma unroll
        for (int r = 0; r < 4; r++) facc[ct][r] = 0.f;
    dense_order(h0, (const uint4*)Wt, Bl, b0, off0, sc0, tid, i, q, arow, facc);
    #pragma unroll
    for (int r = 0; r < 4; r++) {
        int orow = slab + q * 4 + r;
        if (orow < N) {
            float* op = out + (size_t)orow * DD + i;
            #pragma unroll
            for (int ct = 0; ct < 8; ct++)
                __builtin_nontemporal_store(facc[ct][r], op + ct * 16);
        }
    }
}

__global__ __launch_bounds__(256) void spmm2_dense1(
    const uint4* __restrict__ xv, const int* __restrict__ row_ptr,
    const int2* __restrict__ ep, uint4* __restrict__ hop2,
    const unsigned short* __restrict__ h1,
    const unsigned short* __restrict__ Wt,
    const float* __restrict__ b1, const float* __restrict__ off1,
    const float* __restrict__ sc1, float* __restrict__ out, int N)
{
    __shared__ uint4 Bl[2048];
    const int q5 = blockIdx.x / 5;
    const int r5 = blockIdx.x % 5;
    if (r5 < 4) {
        int t = (q5 * 4 + r5) * 256 + threadIdx.x;
        int g = t >> 4;
        int lane = t & 15;
        if (g >= N) return;
        hop2[(size_t)g * 16 + lane] =
            row_gather(xv, ep, row_ptr[g], row_ptr[g + 1], lane);
        return;
    }
    const int tid = threadIdx.x;
    const int wave = tid >> 6;
    const int lane = tid & 63;
    const int i = lane & 15;
    const int q = lane >> 4;
    const int slab = q5 * 64 + wave * 16;
    int arow = slab + i;
    if (arow >= N) arow = N - 1;
    float facc[8][4];
    #pragma unroll
    for (int ct = 0; ct < 8; ct++)
        #pragma unroll
        for (int r = 0; r < 4; r++) facc[ct][r] = 0.f;
    dense_order(h1, (const uint4*)(Wt + DD * DD), Bl, b1, off1, sc1,
                tid, i, q, arow, facc);
    #pragma unroll
    for (int r = 0; r < 4; r++) {
        int orow = slab + q * 4 + r;
        if (orow < N) {
            float* op = out + (size_t)orow * DD + i;
            #pragma unroll
            for (int ct = 0; ct < 8; ct++) {
                float prev = op[ct * 16];
                __builtin_nontemporal_store(prev + facc[ct][r], op + ct * 16);
            }
        }
    }
}

__global__ __launch_bounds__(256) void dense2_final(
    const unsigned short* __restrict__ h2,
    const unsigned short* __restrict__ Wt,
    const float* __restrict__ b2, const float* __restrict__ off2,
    const float* __restrict__ sc2, float* __restrict__ out, int N)
{
    __shared__ uint4 Bl[2048];
    const int tid = threadIdx.x;
    const int wave = tid >> 6;
    const int lane = tid & 63;
    const int i = lane & 15;
    const int q = lane >> 4;
    const int slab = blockIdx.x * 64 + wave * 16;
    int arow = slab + i;
    if (arow >= N) arow = N - 1;
    float facc[8][4];
    #pragma unroll
    for (int ct = 0; ct < 8; ct++)
        #pragma unroll
        for (int r = 0; r < 4; r++) facc[ct][r] = 0.f;
    dense_order(h2, (const uint4*)(Wt + 2 * DD * DD), Bl, b2, off2, sc2,
                tid, i, q, arow, facc);
    #pragma unroll
    for (int r = 0; r < 4; r++) {
        int orow = slab + q * 4 + r;
        if (orow < N) {
            float* op = out + (size_t)orow * DD + i;
            #pragma unroll
            for (int ct = 0; ct < 8; ct++) {
                float prev = op[ct * 16];
                __builtin_nontemporal_store(prev + facc[ct][r], op + ct * 16);
            }
        }
    }
}

extern "C" void kernel_launch(void* const* d_in, const int* in_sizes, int n_in,
                              void* d_out, int out_size, void* d_ws, size_t ws_size,
                              hipStream_t stream)
{
    const float* vecs = (const float*)d_in[0];
    const float* adj  = (const float*)d_in[1];
    const int*   row  = (const int*)d_in[2];
    const int*   col  = (const int*)d_in[3];
    const float* W0   = (const float*)d_in[4];
    const float* b0   = (const float*)d_in[5];
    const float* off0 = (const float*)d_in[6];
    const float* sc0  = (const float*)d_in[7];
    const float* W1   = (const float*)d_in[8];
    const float* b1   = (const float*)d_in[9];
    const float* off1 = (const float*)d_in[10];
    const float* sc1  = (const float*)d_in[11];
    const float* W2   = (const float*)d_in[12];
    const float* b2   = (const float*)d_in[13];
    const float* off2 = (const float*)d_in[14];
    const float* sc2  = (const float*)d_in[15];

    const int E = in_sizes[1];
    const int N = NN;

    // Fixed bucket capacity: avg + 8 sigma (multinomial), 16-rounded.
    const int avg = (E + NB - 1) / NB;
    const int CAP = (avg + 8 * (int)sqrt((double)avg) + 79) & ~15;

    // Workspace layout (all regions 16B-aligned)
    unsigned short* hop1_bf = (unsigned short*)d_ws;          // N*DD bf16
    unsigned short* hop2_bf = hop1_bf + (size_t)N * DD;       // N*DD bf16
    unsigned short* vecs_bf = hop2_bf + (size_t)N * DD;       // N*DD bf16
    unsigned short* Wt_bf   = vecs_bf + (size_t)N * DD;       // 3*DD*DD bf16
    int*   row_ptr  = (int*)(Wt_bf + 3 * DD * DD);            // RP_PAD ints
    int*   bcnt     = row_ptr + RP_PAD;                       // 512 ints
    int2*  ep_raw   = (int2*)(bcnt + 512);                    // NB*CAP (padded)
    int2*  epack    = ep_raw + (size_t)NB * CAP;              // E (dense CSR)

    // Zero bucket cursors (1.5 KB)
    hipMemsetAsync(bcnt, 0, NB * sizeof(int), stream);

    // Merged scatter + converts
    const int cb = (E + 8191) / 8192;
    const int n8 = N * DD / 8;
    const int vb = (n8 + 1023) / 1024;
    scatter_convert<<<cb + 6 + vb, 1024, 0, stream>>>(
        row, col, adj, bcnt, ep_raw, E, CAP, cb,
        vecs, vecs_bf, W0, W1, W2, Wt_bf, n8);

    // CSR compaction
    csr_compact<<<NB, 1024, 0, stream>>>(
        bcnt, ep_raw, row_ptr, epack, CAP, N, E);

    // Co-scheduled: spmm hop-1 (4/5 of blocks) || dense order-0 (1/5)
    const int db = (N + 63) / 64;       // 1563
    const int grid = db * 5;            // 4:1 interleave covers sb=6250 spmm ids
    spmm1_dense0<<<grid, 256, 0, stream>>>(
        (const uint4*)vecs_bf, row_ptr, epack, (uint4*)hop1_bf,
        vecs_bf, Wt_bf, b0, off0, sc0, (float*)d_out, N);

    // Co-scheduled: spmm hop-2 || dense order-1 (accumulates into d_out)
    spmm2_dense1<<<grid, 256, 0, stream>>>(
        (const uint4*)hop1_bf, row_ptr, epack, (uint4*)hop2_bf,
        hop1_bf, Wt_bf, b1, off1, sc1, (float*)d_out, N);

    // Final: dense order-2 (accumulates into d_out)
    dense2_final<<<db, 256, 0, stream>>>(
        hop2_bf, Wt_bf, b2, off2, sc2, (float*)d_out, N);
}

// Round 12
// 335.751 us; speedup vs baseline: 1.1130x; 1.1130x over previous
//
#include <hip/hip_runtime.h>
#include <math.h>

#define NN 100000
#define DD 128
#define NB 391          // row buckets of 256 rows: (100000+255)>>8
#define RP_PAD 100004   // row_ptr elems, padded for 16B alignment

typedef short bf16x8 __attribute__((ext_vector_type(8)));
typedef float f32x4  __attribute__((ext_vector_type(4)));
typedef unsigned uint4v __attribute__((ext_vector_type(4)));

__device__ __forceinline__ unsigned f2bf_rne(float f) {
    unsigned u = __float_as_uint(f);
    return (u + 0x7FFFu + ((u >> 16) & 1u)) >> 16;
}
__device__ __forceinline__ unsigned packbf(float a, float b) {
    return f2bf_rne(a) | (f2bf_rne(b) << 16);
}
__device__ __forceinline__ float bf_lo(unsigned u) { return __uint_as_float(u << 16); }
__device__ __forceinline__ float bf_hi(unsigned u) { return __uint_as_float(u & 0xFFFF0000u); }

// non-temporal 8B edge load — CSR-build use only (single-pass streams).
// NOT used in spmm: round-1 measured NT there at +36MB fetch, -10% BW,
// +28% time (breaks load merging; edge stream was L2-resident anyway).
__device__ __forceinline__ int2 ldnt_edge(const int2* p) {
    long long v = __builtin_nontemporal_load((const long long*)p);
    int2 r;
    r.x = (int)(v & 0xffffffffll);
    r.y = (int)(((unsigned long long)v) >> 32);
    return r;
}

// ---------------------------------------------------------------------------
// Bucketed CSR build, fixed-capacity buckets (CAP = avg + 8 sigma).
// Bucketing is ESSENTIAL (rounds 4+7: randomly-addressed global RMWs are
// line-churn bound — keep ALL random RMWs in LDS). Geometry (rounds 5/6):
// 8192-edge chunks x 1024 threads. Round-8: edges register-cached in the
// hist loop (static unroll, no scratch) so the scatter loop has no global
// loads. Record = (col | row_lo<<17, val).
// ---------------------------------------------------------------------------
__global__ __launch_bounds__(1024) void bucket_scatter(
    const int* __restrict__ row, const int* __restrict__ col,
    const float* __restrict__ vals, int* __restrict__ bcnt,
    int2* __restrict__ ep_raw, int E, int CAP)
{
    __shared__ int cnt[NB];
    __shared__ int base[NB];
    const int t = threadIdx.x;
    if (t < NB) cnt[t] = 0;
    __syncthreads();
    const int cb = blockIdx.x * 8192;
    const int ce = min(cb + 8192, E);

    int   rr[8];
    int   cc[8];
    float vv[8];
    #pragma unroll
    for (int i = 0; i < 8; i++) {
        int j = cb + t + i * 1024;
        bool ok = j < ce;
        rr[i] = -1;
        if (ok) {
            rr[i] = row[j];
            cc[i] = __builtin_nontemporal_load(col + j);
            vv[i] = __builtin_nontemporal_load(vals + j);
            atomicAdd(&cnt[rr[i] >> 8], 1);
        }
    }
    __syncthreads();
    if (t < NB) {
        int c = cnt[t];
        base[t] = c ? (t * CAP + atomicAdd(&bcnt[t], c)) : 0;
        cnt[t] = 0;
    }
    __syncthreads();
    #pragma unroll
    for (int i = 0; i < 8; i++) {
        int r = rr[i];
        if (r >= 0) {
            int b = r >> 8;
            int off = atomicAdd(&cnt[b], 1);
            unsigned meta = (unsigned)cc[i] | ((unsigned)(r & 255) << 17);
            ep_raw[base[b] + off] = make_int2((int)meta, __float_as_int(vv[i]));
        }
    }
}

// ---------------------------------------------------------------------------
// Merged kernel: CSR compaction (blocks 0..NB-1, inline per-block prefix
// over bcnt) + weight convert (blocks NB..NB+23) + vecs f32->bf16 convert
// (remaining blocks). Convert blocks fill the GPU during compaction's
// atomic-bound tail. Per-bucket LDS hist over the L2-hot 33KB span is the
// right design (round-7: global row hist = line churn).
// ---------------------------------------------------------------------------
__global__ __launch_bounds__(256) void csr_finish_convert(
    const int* __restrict__ bcnt, const int2* __restrict__ ep_raw,
    int* __restrict__ row_ptr, int2* __restrict__ ep,
    const float* __restrict__ vecs, unsigned short* __restrict__ vecs_bf,
    const float* __restrict__ W0, const float* __restrict__ W1,
    const float* __restrict__ W2, unsigned short* __restrict__ Wt,
    int CAP, int N, int E, int n8)
{
    const int b = blockIdx.x;
    const int t = threadIdx.x;

    if (b >= NB) {
        if (b < NB + 24) {
            // ---- W0/W1/W2 f32 -> Wt bf16 [o][n][k] ----
            const int b2 = b - NB;
            const float* W = (b2 < 8) ? W0 : ((b2 < 16) ? W1 : W2);
            unsigned short* dst = Wt + (b2 >> 3) * DD * DD;
            int idx = (b2 & 7) * 256 + t;      // 0..2047
            int n = idx >> 4;
            int kc = (idx & 15) * 8;
            unsigned r[4];
            #pragma unroll
            for (int j = 0; j < 4; j++) {
                float a = W[(kc + 2 * j) * DD + n];
                float c = W[(kc + 2 * j + 1) * DD + n];
                r[j] = packbf(a, c);
            }
            *(uint4*)(dst + n * DD + kc) = make_uint4(r[0], r[1], r[2], r[3]);
        } else {
            // ---- vecs f32 -> bf16, 8 elems/thread ----
            int i = (b - NB - 24) * 256 + t;
            if (i >= n8) return;
            f32x4 a = __builtin_nontemporal_load((const f32x4*)vecs + (size_t)i * 2);
            f32x4 c = __builtin_nontemporal_load((const f32x4*)vecs + (size_t)i * 2 + 1);
            uint4v o;
            o.x = packbf(a.x, a.y); o.y = packbf(a.z, a.w);
            o.z = packbf(c.x, c.y); o.w = packbf(c.z, c.w);
            ((uint4v*)vecs_bf)[i] = o;
        }
        return;
    }

    // ---- CSR compaction for bucket b ----
    __shared__ int red[256];
    __shared__ int rcnt[256];
    __shared__ int rcur[256];
    __shared__ int wsum[4];

    // inline exclusive prefix: dst = sum(bcnt[0..b))
    int part = 0;
    for (int j = t; j < b; j += 256) part += bcnt[j];
    red[t] = part;
    __syncthreads();
    #pragma unroll
    for (int off = 128; off > 0; off >>= 1) {
        if (t < off) red[t] += red[t + off];
        __syncthreads();
    }
    const int dst = red[0];
    const int cnt = bcnt[b];
    const int src = b * CAP;

    rcnt[t] = 0;
    __syncthreads();
    for (int j = t; j < cnt; j += 256)
        atomicAdd(&rcnt[(unsigned)ep_raw[src + j].x >> 17], 1);
    __syncthreads();

    // exclusive scan of 256 counts (4 wave-scans + combine)
    int v = rcnt[t];
    int lane = t & 63;
    int inc = v;
    #pragma unroll
    for (int off = 1; off < 64; off <<= 1) {
        int u = __shfl_up(inc, off, 64);
        if (lane >= off) inc += u;
    }
    if (lane == 63) wsum[t >> 6] = inc;
    __syncthreads();
    int woff = 0;
    for (int i = 0; i < (t >> 6); i++) woff += wsum[i];
    int excl = woff + inc - v;

    int grow = b * 256 + t;
    if (grow < N) row_ptr[grow] = dst + excl;
    rcur[t] = excl;
    __syncthreads();

    for (int j = t; j < cnt; j += 256) {
        int2 rec = ldnt_edge(ep_raw + src + j);
        unsigned meta = (unsigned)rec.x;
        int rlo = meta >> 17;
        int c = (int)(meta & 0x1FFFFu);
        int p = atomicAdd(&rcur[rlo], 1);
        ep[dst + p] = make_int2(c, rec.y);
    }
    if (b == 0 && t == 0) row_ptr[N] = E;
}

// ---------------------------------------------------------------------------
// Gather SpMM (CSR, bf16, packed edges): one row per 16-lane group,
// 8 bf16 (16B) per lane. fp32 accumulate, bf16 output. CACHED loads/stores
// (round-1 NT regression). FETCH 183MB == private-L2 compulsory floor for
// uniform-random gather (8 XCDs x (1-e^-2) x 25.6MB + edges); 3.4 TB/s is
// the random-granule fabric rate. Rounds 9+11: NEVER couple this gather
// with the MFMA context — intra-block fusion (r9) and intra-kernel block
// interleave (r11, static 32KB LDS applies to every block) both collapse
// its TLP to ~2x slower. Keep it in its own lean max-occupancy kernel.
// Structural floor.
// ---------------------------------------------------------------------------
__device__ __forceinline__ void accum8(float* acc, uint4 u, float v) {
    acc[0] += v * bf_lo(u.x); acc[1] += v * bf_hi(u.x);
    acc[2] += v * bf_lo(u.y); acc[3] += v * bf_hi(u.y);
    acc[4] += v * bf_lo(u.z); acc[5] += v * bf_hi(u.z);
    acc[6] += v * bf_lo(u.w); acc[7] += v * bf_hi(u.w);
}

__global__ __launch_bounds__(256) void spmm_bf16(
    const uint4* __restrict__ x, const int* __restrict__ row_ptr,
    const int2* __restrict__ ep, uint4* __restrict__ out, int N)
{
    int t = blockIdx.x * 256 + threadIdx.x;
    int g = t >> 4;
    int lane = t & 15;
    if (g >= N) return;

    int s = row_ptr[g];
    int e = row_ptr[g + 1];
    float acc[8] = {0.f, 0.f, 0.f, 0.f, 0.f, 0.f, 0.f, 0.f};

    int k = s;
    for (; k + 8 <= e; k += 8) {
        int2 E0 = ep[k + 0], E1 = ep[k + 1], E2 = ep[k + 2], E3 = ep[k + 3];
        int2 E4 = ep[k + 4], E5 = ep[k + 5], E6 = ep[k + 6], E7 = ep[k + 7];
        uint4 X0 = x[(size_t)E0.x * 16 + lane];
        uint4 X1 = x[(size_t)E1.x * 16 + lane];
        uint4 X2 = x[(size_t)E2.x * 16 + lane];
        uint4 X3 = x[(size_t)E3.x * 16 + lane];
        uint4 X4 = x[(size_t)E4.x * 16 + lane];
        uint4 X5 = x[(size_t)E5.x * 16 + lane];
        uint4 X6 = x[(size_t)E6.x * 16 + lane];
        uint4 X7 = x[(size_t)E7.x * 16 + lane];
        accum8(acc, X0, __int_as_float(E0.y));
        accum8(acc, X1, __int_as_float(E1.y));
        accum8(acc, X2, __int_as_float(E2.y));
        accum8(acc, X3, __int_as_float(E3.y));
        accum8(acc, X4, __int_as_float(E4.y));
        accum8(acc, X5, __int_as_float(E5.y));
        accum8(acc, X6, __int_as_float(E6.y));
        accum8(acc, X7, __int_as_float(E7.y));
    }
    for (; k + 4 <= e; k += 4) {
        int2 E0 = ep[k + 0], E1 = ep[k + 1], E2 = ep[k + 2], E3 = ep[k + 3];
        uint4 X0 = x[(size_t)E0.x * 16 + lane];
        uint4 X1 = x[(size_t)E1.x * 16 + lane];
        uint4 X2 = x[(size_t)E2.x * 16 + lane];
        uint4 X3 = x[(size_t)E3.x * 16 + lane];
        accum8(acc, X0, __int_as_float(E0.y));
        accum8(acc, X1, __int_as_float(E1.y));
        accum8(acc, X2, __int_as_float(E2.y));
        accum8(acc, X3, __int_as_float(E3.y));
    }
    for (; k < e; k++) {
        int2 E0 = ep[k];
        uint4 X0 = x[(size_t)E0.x * 16 + lane];
        accum8(acc, X0, __int_as_float(E0.y));
    }

    uint4 o;
    o.x = packbf(acc[0], acc[1]); o.y = packbf(acc[2], acc[3]);
    o.z = packbf(acc[4], acc[5]); o.w = packbf(acc[6], acc[7]);
    out[(size_t)g * 16 + lane] = o;
}

// ---------------------------------------------------------------------------
// Fused dense via bf16 MFMA 16x16x32. One 64-row slab per block (4 waves x
// 16 rows). Per order: stage W^T (32 KB) into LDS in [kc][n] layout, B-frags
// from LDS, A-frags direct from global (read-once, nt). Per-row batchnorm via
// C-layout + shfl_xor{1,2,4,8}.
// ---------------------------------------------------------------------------
__device__ __forceinline__ void bn_accum(
    f32x4* acc, const float* __restrict__ bias, const float* __restrict__ off,
    const float* __restrict__ sc, int i, float facc[8][4])
{
    float bc[8], sv[8], ov[8];
    #pragma unroll
    for (int ct = 0; ct < 8; ct++) {
        int c = ct * 16 + i;
        bc[ct] = bias[c]; sv[ct] = sc[c]; ov[ct] = off[c];
    }
    float s[4] = {0.f, 0.f, 0.f, 0.f};
    float qq[4] = {0.f, 0.f, 0.f, 0.f};
    #pragma unroll
    for (int ct = 0; ct < 8; ct++) {
        #pragma unroll
        for (int r = 0; r < 4; r++) {
            float v = fmaxf(acc[ct][r] + bc[ct], 0.f);
            acc[ct][r] = v;
            s[r] += v;
            qq[r] += v * v;
        }
    }
    #pragma unroll
    for (int r = 0; r < 4; r++) {
        #pragma unroll
        for (int m = 1; m <= 8; m <<= 1) {
            s[r]  += __shfl_xor(s[r],  m, 64);
            qq[r] += __shfl_xor(qq[r], m, 64);
        }
    }
    #pragma unroll
    for (int r = 0; r < 4; r++) {
        float mn = s[r] * 0.0078125f;
        float var = qq[r] * 0.0078125f - mn * mn;
        float rs = rsqrtf(var + 1e-9f);
        #pragma unroll
        for (int ct = 0; ct < 8; ct++)
            facc[ct][r] += sv[ct] * (acc[ct][r] - mn) * rs + ov[ct];
    }
}

__global__ __launch_bounds__(256) void fused_dense_mfma(
    const unsigned short* __restrict__ h0,
    const unsigned short* __restrict__ h1,
    const unsigned short* __restrict__ h2,
    const unsigned short* __restrict__ Wt,   // [3][128][128] bf16, [o][n][k]
    const float* __restrict__ b0, const float* __restrict__ b1,
    const float* __restrict__ b2,
    const float* __restrict__ off0, const float* __restrict__ off1,
    const float* __restrict__ off2,
    const float* __restrict__ sc0, const float* __restrict__ sc1,
    const float* __restrict__ sc2,
    float* __restrict__ out, int N)
{
    __shared__ uint4 Bl[2048];   // 32 KB: current order's W^T, (kc,n) at kc*128+n

    const int tid  = threadIdx.x;
    const int wave = tid >> 6;
    const int lane = tid & 63;
    const int i    = lane & 15;   // tile col / A-row
    const int q    = lane >> 4;   // quad
    const int slab = blockIdx.x * 64 + wave * 16;

    int arow = slab + i;
    if (arow >= N) arow = N - 1;

    const unsigned short* hops[3] = {h0, h1, h2};
    const float* bs[3]  = {b0, b1, b2};
    const float* ofs[3] = {off0, off1, off2};
    const float* scs[3] = {sc0, sc1, sc2};
    const bf16x8* Bv = (const bf16x8*)Bl;

    float facc[8][4];
    #pragma unroll
    for (int ct = 0; ct < 8; ct++)
        #pragma unroll
        for (int r = 0; r < 4; r++) facc[ct][r] = 0.f;

    for (int o = 0; o < 3; o++) {
        const uint4* Wg = (const uint4*)(Wt + o * DD * DD);
        #pragma unroll
        for (int j = 0; j < 8; j++) {
            int c  = j * 256 + tid;
            int nn = c & 127;
            int kc = c >> 7;
            Bl[kc * 128 + nn] = Wg[nn * 16 + kc];
        }
        __syncthreads();

        const unsigned short* arow_p = hops[o] + (size_t)arow * DD + q * 8;
        f32x4 acc[8];
        #pragma unroll
        for (int ct = 0; ct < 8; ct++) acc[ct] = (f32x4){0.f, 0.f, 0.f, 0.f};
        #pragma unroll
        for (int kb = 0; kb < 4; kb++) {
            bf16x8 a = __builtin_nontemporal_load((const bf16x8*)(arow_p + kb * 32));
            const int kc = kb * 4 + q;
            #pragma unroll
            for (int ct = 0; ct < 8; ct++) {
                bf16x8 b = Bv[kc * 128 + ct * 16 + i];
                acc[ct] = __builtin_amdgcn_mfma_f32_16x16x32_bf16(a, b, acc[ct], 0, 0, 0);
            }
        }
        bn_accum(acc, bs[o], ofs[o], scs[o], i, facc);
        __syncthreads();
    }

    #pragma unroll
    for (int r = 0; r < 4; r++) {
        int orow = slab + q * 4 + r;
        if (orow < N) {
            float* op = out + (size_t)orow * DD + i;
            #pragma unroll
            for (int ct = 0; ct < 8; ct++)
                __builtin_nontemporal_store(facc[ct][r], op + ct * 16);
        }
    }
}

extern "C" void kernel_launch(void* const* d_in, const int* in_sizes, int n_in,
                              void* d_out, int out_size, void* d_ws, size_t ws_size,
                              hipStream_t stream)
{
    const float* vecs = (const float*)d_in[0];
    const float* adj  = (const float*)d_in[1];
    const int*   row  = (const int*)d_in[2];
    const int*   col  = (const int*)d_in[3];
    const float* W0   = (const float*)d_in[4];
    const float* b0   = (const float*)d_in[5];
    const float* off0 = (const float*)d_in[6];
    const float* sc0  = (const float*)d_in[7];
    const float* W1   = (const float*)d_in[8];
    const float* b1   = (const float*)d_in[9];
    const float* off1 = (const float*)d_in[10];
    const float* sc1  = (const float*)d_in[11];
    const float* W2   = (const float*)d_in[12];
    const float* b2   = (const float*)d_in[13];
    const float* off2 = (const float*)d_in[14];
    const float* sc2  = (const float*)d_in[15];

    const int E = in_sizes[1];
    const int N = NN;

    // Fixed bucket capacity: avg + 8 sigma (multinomial), 16-rounded.
    const int avg = (E + NB - 1) / NB;
    const int CAP = (avg + 8 * (int)sqrt((double)avg) + 79) & ~15;

    // Workspace layout (all regions 16B-aligned)
    unsigned short* hop1_bf = (unsigned short*)d_ws;          // N*DD bf16
    unsigned short* hop2_bf = hop1_bf + (size_t)N * DD;       // N*DD bf16
    unsigned short* vecs_bf = hop2_bf + (size_t)N * DD;       // N*DD bf16
    unsigned short* Wt_bf   = vecs_bf + (size_t)N * DD;       // 3*DD*DD bf16
    int*   row_ptr  = (int*)(Wt_bf + 3 * DD * DD);            // RP_PAD ints
    int*   bcnt     = row_ptr + RP_PAD;                       // 512 ints
    int2*  ep_raw   = (int2*)(bcnt + 512);                    // NB*CAP (padded)
    int2*  epack    = ep_raw + (size_t)NB * CAP;              // E (dense CSR)

    // Zero bucket cursors (1.5 KB)
    hipMemsetAsync(bcnt, 0, NB * sizeof(int), stream);

    // Bucketed scatter: 8192-edge chunks x 1024 threads, register-cached edges
    const int cb = (E + 8191) / 8192;
    bucket_scatter<<<cb, 1024, 0, stream>>>(row, col, adj, bcnt, ep_raw, E, CAP);

    // Merged: CSR compaction (inline per-block prefix) + W convert + vecs convert
    const int n8 = N * DD / 8;
    const int vb = (n8 + 255) / 256;
    csr_finish_convert<<<NB + 24 + vb, 256, 0, stream>>>(
        bcnt, ep_raw, row_ptr, epack,
        vecs, vecs_bf, W0, W1, W2, Wt_bf,
        CAP, N, E, n8);

    // SpMM hops (bf16 in/out, fp32 accumulate)
    int sb = (N * 16 + 255) / 256;
    spmm_bf16<<<sb, 256, 0, stream>>>(
        (const uint4*)vecs_bf, row_ptr, epack, (uint4*)hop1_bf, N);
    spmm_bf16<<<sb, 256, 0, stream>>>(
        (const uint4*)hop1_bf, row_ptr, epack, (uint4*)hop2_bf, N);

    // Fused dense (MFMA, per-order LDS-staged B)
    const int db = (N + 63) / 64;
    fused_dense_mfma<<<db, 256, 0, stream>>>(
        vecs_bf, hop1_bf, hop2_bf, Wt_bf,
        b0, b1, b2, off0, off1, off2, sc0, sc1, sc2,
        (float*)d_out, N);
}